// Round 1
// baseline (167.347 us; speedup 1.0000x reference)
//
#include <hip/hip_runtime.h>
#include <math.h>

#define NQ   16
#define NL   4
#define ND   256
#define NB   512
#define NTH  256
#define SLOT 544   // float2 per tensor slot (>= 15*33+16+15+1)
#define ASTR 33    // alpha stride in tensor layout: idx = a*33 + i*16 + b
#define TPAD 17    // padded row stride for 16x16 scratch (bank-conflict-free)

typedef float2 c32;

__device__ __forceinline__ c32 cmul(c32 a, c32 b) {
    return make_float2(a.x*b.x - a.y*b.y, a.x*b.y + a.y*b.x);
}
__device__ __forceinline__ c32 cfma_(c32 a, c32 b, c32 acc) {
    // acc += a*b
    acc.x = fmaf(a.x, b.x, fmaf(-a.y, b.y, acc.x));
    acc.y = fmaf(a.x, b.y, fmaf( a.y, b.x, acc.y));
    return acc;
}
__device__ __forceinline__ c32 cfmaConjA(c32 a, c32 b, c32 acc) {
    // acc += conj(a)*b
    acc.x = fmaf(a.x, b.x, fmaf( a.y, b.y, acc.x));
    acc.y = fmaf(a.x, b.y, fmaf(-a.y, b.x, acc.y));
    return acc;
}
__device__ __forceinline__ c32 cmulConjA(c32 a, c32 b) {
    return cfmaConjA(a, b, make_float2(0.f, 0.f));
}
__device__ __forceinline__ c32 cadd(c32 a, c32 b){ return make_float2(a.x+b.x, a.y+b.y); }
__device__ __forceinline__ c32 csub(c32 a, c32 b){ return make_float2(a.x-b.x, a.y-b.y); }

__global__ __launch_bounds__(NTH, 1)
void pqc_mps_kernel(const float* __restrict__ ctx,
                    const float* __restrict__ Wm,
                    const float* __restrict__ bias,
                    const float* __restrict__ params,
                    float* __restrict__ out)
{
    __shared__ c32 bufA[NQ * SLOT];   // 69632 B
    __shared__ c32 bufB[NQ * SLOT];   // 69632 B
    __shared__ c32 Ug[NL * NQ * 4];   // fused RZ*RY*RX per (l,q)
    __shared__ float angles[NQ];
    __shared__ float red[4];
    __shared__ float zres[NQ];

    const int b   = blockIdx.x;
    const int tid = threadIdx.x;

    // ---------------- encoding angles: pi*tanh(ctx[b]·W[q] + bias[q]) -------
    {
        const int q = tid >> 4, g = tid & 15;
        const float* crow = ctx + b * ND;
        const float* wrow = Wm + q * ND;
        float s = 0.f;
        #pragma unroll
        for (int j = 0; j < ND / 16; ++j)
            s += crow[g + 16*j] * wrow[g + 16*j];
        #pragma unroll
        for (int m = 8; m; m >>= 1) s += __shfl_xor(s, m);  // reduce 16-lane group
        if (g == 0) angles[q] = 3.14159265358979323846f * tanhf(s + bias[q]);
    }

    // ---------------- fused gates U = RZ*RY*RX per (l,q) --------------------
    if (tid < NL * NQ) {
        const float a  = params[tid*3 + 0];
        const float bb = params[tid*3 + 1];
        const float c  = params[tid*3 + 2];
        const float ha = 0.5f*a, hb = 0.5f*bb, hc = 0.5f*c;
        const float ca = cosf(ha), sa = sinf(ha);
        const float cb = cosf(hb), sb = sinf(hb);
        const float cz = cosf(hc), sz = sinf(hc);
        // M = RY*RX  (derived by hand, verified):
        const c32 m00 = make_float2( cb*ca,  sb*sa);
        const c32 m01 = make_float2(-sb*ca, -cb*sa);
        const c32 m10 = make_float2( sb*ca, -cb*sa);
        const c32 m11 = make_float2( cb*ca, -sb*sa);
        const c32 e0 = make_float2(cz, -sz);   // e^{-i hc}
        const c32 e1 = make_float2(cz,  sz);   // e^{+i hc}
        Ug[tid*4 + 0] = cmul(e0, m00);
        Ug[tid*4 + 1] = cmul(e0, m01);
        Ug[tid*4 + 2] = cmul(e1, m10);
        Ug[tid*4 + 3] = cmul(e1, m11);
    }
    __syncthreads();

    // ---------------- encoding product state: A_q = RX(angle_q)|0> ----------
    if (tid < NQ) {
        const float h = 0.5f * angles[tid];
        bufA[tid*SLOT + 0]  = make_float2(cosf(h), 0.f);   // (a=0,i=0,b=0)
        bufA[tid*SLOT + 16] = make_float2(0.f, -sinf(h));  // (a=0,i=1,b=0)
    }
    __syncthreads();

    // ---------------- variational layers: chi -> 2*chi ----------------------
    // per tensor q: out[(k,a), i, (k',b)] = (i==k') ? sum_j U[i^k, j]*in[a,j,b] : 0
    #pragma unroll
    for (int l = 0; l < NL; ++l) {
        const int chi = 1 << l;                    // entering bond dim
        const c32* src = (l & 1) ? bufB : bufA;
        c32*       dst = (l & 1) ? bufA : bufB;

        for (int q = 0; q < NQ - 1; ++q) {         // crOut = 2*chi (const)
            const c32* in = src + q * SLOT;
            c32*       op = dst + q * SLOT;
            const c32 U00 = Ug[(l*NQ+q)*4+0], U01 = Ug[(l*NQ+q)*4+1];
            const c32 U10 = Ug[(l*NQ+q)*4+2], U11 = Ug[(l*NQ+q)*4+3];
            const int crOut = 2 * chi;
            const int clOut = (q == 0) ? 1 : 2 * chi;
            const int N = clOut * 2 * crOut;
            for (int t = tid; t < N; t += NTH) {
                const int bo = t % crOut;
                const int i  = (t / crOut) & 1;
                const int ao = t / (2 * crOut);
                const int k  = (q == 0) ? 0 : (ao / chi);
                const int al = (q == 0) ? 0 : (ao % chi);
                const int kp = bo / chi;
                const int bl = bo % chi;
                c32 val = make_float2(0.f, 0.f);
                if (i == kp) {
                    const int row = i ^ k;
                    const c32 u0 = (row == 0) ? U00 : U10;
                    const c32 u1 = (row == 0) ? U01 : U11;
                    const c32 a0 = in[al*ASTR + 0  + bl];
                    const c32 a1 = in[al*ASTR + 16 + bl];
                    val = cfma_(u0, a0, cfma_(u1, a1, make_float2(0.f,0.f)));
                }
                op[ao*ASTR + i*16 + bo] = val;
            }
        }
        {   // q = 15: target-role only, crOut = 1
            const int q = NQ - 1;
            const c32* in = src + q * SLOT;
            c32*       op = dst + q * SLOT;
            const c32 U00 = Ug[(l*NQ+q)*4+0], U01 = Ug[(l*NQ+q)*4+1];
            const c32 U10 = Ug[(l*NQ+q)*4+2], U11 = Ug[(l*NQ+q)*4+3];
            const int N = (2 * chi) * 2;
            for (int t = tid; t < N; t += NTH) {
                const int i  = t & 1;
                const int ao = t >> 1;
                const int k  = ao / chi;
                const int al = ao % chi;
                const int row = i ^ k;
                const c32 u0 = (row == 0) ? U00 : U10;
                const c32 u1 = (row == 0) ? U01 : U11;
                const c32 a0 = in[al*ASTR + 0];
                const c32 a1 = in[al*ASTR + 16];
                op[ao*ASTR + i*16] = cfma_(u0, a0, cfma_(u1, a1, make_float2(0.f,0.f)));
            }
        }
        __syncthreads();
    }
    // final MPS (chi=16 everywhere) now in bufA; bufB is free -> environments.

    c32* Renv = bufB;                     // R_q at q*256, q = 0..14 (16x16 each)
    c32* Tsc  = bufB + 15*256;            // 16x16 scratch, row stride TPAD
    c32* Lbuf = bufB + 15*256 + 16*TPAD;  // 16x16 left env, row stride TPAD

    const int r  = tid >> 4;   // row
    const int cc = tid & 15;   // col

    // ---------------- R sweep ----------------------------------------------
    {   // site 15: R_14[b,b'] = sum_i conj(A15[b,i,0]) A15[b',i,0]
        const c32* A15 = bufA + 15*SLOT;
        c32 acc = make_float2(0.f, 0.f);
        #pragma unroll
        for (int i = 0; i < 2; ++i)
            acc = cfmaConjA(A15[r*ASTR + i*16], A15[cc*ASTR + i*16], acc);
        Renv[14*256 + tid] = acc;
    }
    __syncthreads();

    for (int q = 13; q >= 0; --q) {
        const c32* As = bufA + (q+1)*SLOT;
        const c32* Rn = Renv + (q+1)*256;
        c32 racc = make_float2(0.f, 0.f);
        #pragma unroll
        for (int i = 0; i < 2; ++i) {
            // T[b,g'] = sum_g conj(As[b,i,g]) Rn[g,g']
            c32 t = make_float2(0.f, 0.f);
            #pragma unroll
            for (int g = 0; g < 16; ++g)
                t = cfmaConjA(As[r*ASTR + i*16 + g], Rn[g*16 + cc], t);
            Tsc[r*TPAD + cc] = t;
            __syncthreads();
            // R_q[b,b'] += sum_g' T[b,g'] As[b',i,g']
            #pragma unroll
            for (int g = 0; g < 16; ++g)
                racc = cfma_(Tsc[r*TPAD + g], As[cc*ASTR + i*16 + g], racc);
            __syncthreads();
        }
        Renv[q*256 + tid] = racc;
        __syncthreads();
    }

    // ---------------- L sweep + <Z_q> ---------------------------------------
    {   // site 0: S_i[b,b'] = conj(A0[0,i,b]) A0[0,i,b']
        const c32* A0 = bufA;
        const c32 S0 = cmulConjA(A0[0  + r], A0[0  + cc]);
        const c32 S1 = cmulConjA(A0[16 + r], A0[16 + cc]);
        const c32 R0 = Renv[tid];
        const c32 dS = csub(S0, S1);
        float val = dS.x*R0.x - dS.y*R0.y;
        #pragma unroll
        for (int m = 32; m; m >>= 1) val += __shfl_xor(val, m);
        if ((tid & 63) == 0) red[tid >> 6] = val;
        Lbuf[r*TPAD + cc] = cadd(S0, S1);
        __syncthreads();
        if (tid == 0) zres[0] = red[0] + red[1] + red[2] + red[3];
        __syncthreads();
    }

    for (int s = 1; s < 15; ++s) {
        const c32* As = bufA + s*SLOT;
        c32 S0 = make_float2(0.f,0.f), S1 = make_float2(0.f,0.f);
        #pragma unroll
        for (int i = 0; i < 2; ++i) {
            // T[a,b'] = sum_a' L[a,a'] As[a',i,b']
            c32 t = make_float2(0.f, 0.f);
            #pragma unroll
            for (int g = 0; g < 16; ++g)
                t = cfma_(Lbuf[r*TPAD + g], As[g*ASTR + i*16 + cc], t);
            Tsc[r*TPAD + cc] = t;
            __syncthreads();
            // S_i[b,b'] = sum_a conj(As[a,i,b]) T[a,b']
            c32 sacc = make_float2(0.f, 0.f);
            #pragma unroll
            for (int g = 0; g < 16; ++g)
                sacc = cfmaConjA(As[g*ASTR + i*16 + r], Tsc[g*TPAD + cc], sacc);
            if (i == 0) S0 = sacc; else S1 = sacc;
            __syncthreads();
        }
        const c32 Rq = Renv[s*256 + tid];
        const c32 dS = csub(S0, S1);
        float val = dS.x*Rq.x - dS.y*Rq.y;
        #pragma unroll
        for (int m = 32; m; m >>= 1) val += __shfl_xor(val, m);
        if ((tid & 63) == 0) red[tid >> 6] = val;
        Lbuf[r*TPAD + cc] = cadd(S0, S1);
        __syncthreads();
        if (tid == 0) zres[s] = red[0] + red[1] + red[2] + red[3];
        __syncthreads();
    }

    {   // site 15: <Z_15> = Re sum L[a,a'] (conj(A[a,0])A[a',0] - conj(A[a,1])A[a',1])
        const c32* A15 = bufA + 15*SLOT;
        const c32 d = csub(cmulConjA(A15[r*ASTR     ], A15[cc*ASTR     ]),
                           cmulConjA(A15[r*ASTR + 16], A15[cc*ASTR + 16]));
        const c32 Lv = Lbuf[r*TPAD + cc];
        float val = Lv.x*d.x - Lv.y*d.y;
        #pragma unroll
        for (int m = 32; m; m >>= 1) val += __shfl_xor(val, m);
        if ((tid & 63) == 0) red[tid >> 6] = val;
        __syncthreads();
        if (tid == 0) zres[15] = red[0] + red[1] + red[2] + red[3];
        __syncthreads();
    }

    if (tid < NQ) out[b*NQ + tid] = zres[tid];
}

extern "C" void kernel_launch(void* const* d_in, const int* in_sizes, int n_in,
                              void* d_out, int out_size, void* d_ws, size_t ws_size,
                              hipStream_t stream) {
    const float* ctx    = (const float*)d_in[0];   // [512,256]
    const float* Wm     = (const float*)d_in[1];   // [16,256]
    const float* bias   = (const float*)d_in[2];   // [16]
    const float* params = (const float*)d_in[3];   // [4,16,3]
    float* out = (float*)d_out;                    // [512,16]
    (void)in_sizes; (void)n_in; (void)out_size; (void)d_ws; (void)ws_size;
    pqc_mps_kernel<<<NB, NTH, 0, stream>>>(ctx, Wm, bias, params, out);
}

// Round 2
// 79.424 us; speedup vs baseline: 2.1070x; 2.1070x over previous
//
#include <hip/hip_runtime.h>
#include <math.h>

#define NQ   16
#define NTH  256
#define NB   512

typedef float2 c32;

__device__ __forceinline__ c32 cmul(c32 a, c32 b) {
    return make_float2(a.x*b.x - a.y*b.y, a.x*b.y + a.y*b.x);
}
__device__ __forceinline__ c32 cfma_(c32 a, c32 b, c32 acc) {
    // acc += a*b
    acc.x = fmaf(a.x, b.x, fmaf(-a.y, b.y, acc.x));
    acc.y = fmaf(a.x, b.y, fmaf( a.y, b.x, acc.y));
    return acc;
}
__device__ __forceinline__ c32 cfmaConjA(c32 a, c32 b, c32 acc) {
    // acc += conj(a)*b
    acc.x = fmaf(a.x, b.x, fmaf( a.y, b.y, acc.x));
    acc.y = fmaf(a.x, b.y, fmaf(-a.y, b.x, acc.y));
    return acc;
}
__device__ __forceinline__ c32 cmulConjA(c32 a, c32 b) {
    return cfmaConjA(a, b, make_float2(0.f, 0.f));
}
__device__ __forceinline__ c32 cadd(c32 a, c32 b){ return make_float2(a.x+b.x, a.y+b.y); }

// Compact MPS representation (right-bond top bit == physical index):
//   interior sites q=1..14:  Ac[a, i, r] = U3[i^k3,m2]*U2[m2^k2,m1]*U1[m1^k1,m0]*w[k0,m0]
//     a=(k3k2k1k0) left bond, i phys, full right bond = i*8 + r, r=(m2m1m0)
//   site 0: A0c[i, r] (left bond trivial); site 15: A15[a, i] (no right constraint, dense sums)
// All L/R environments live on the two diagonal 8x8 blocks only.

__global__ __launch_bounds__(NTH, 2)
void pqc_mps_kernel(const float* __restrict__ ctx,
                    const float* __restrict__ Wm,
                    const float* __restrict__ bias,
                    const float* __restrict__ params,
                    float* __restrict__ out)
{
    __shared__ c32 Ac[14][272];     // sites 1..14; layout a*17 + i*8 + r
    __shared__ c32 A0c[16];         // i*8 + r
    __shared__ c32 A15v[32];        // a*2 + i
    __shared__ c32 Renv[15][144];   // R_q diag blocks: m*72 + bl*9 + bp
    __shared__ c32 Ssto[15][144];   // S at site q, same layout (block index = phys i)
    __shared__ c32 TR[272];         // R-sweep scratch: b*17 + i*8 + g'
    __shared__ c32 TL[272];         // L-sweep scratch: a*17 + i*8 + b'
    __shared__ c32 Lbuf[144];       // running L env, diag blocks
    __shared__ c32 Ug[256];         // fused RZ*RY*RX per (l,q): (l*16+q)*4 + row*2 + col
    __shared__ c32 wv[64];          // w[q,k,i] = sum_j U0q[i^k,j] v_q[j]: q*4 + k*2 + i
    __shared__ float angles[NQ];

    const int b = blockIdx.x;
    const int t = threadIdx.x;

    // ---- phase A: encoding angles + fused gates -----------------------------
    {
        const int q = t >> 4, g = t & 15;
        const float* crow = ctx + b * 256;
        const float* wrow = Wm + q * 256;
        float s = 0.f;
        #pragma unroll
        for (int j = 0; j < 16; ++j)
            s += crow[g + 16*j] * wrow[g + 16*j];
        #pragma unroll
        for (int m = 8; m; m >>= 1) s += __shfl_xor(s, m);
        if (g == 0) angles[q] = 3.14159265358979323846f * tanhf(s + bias[q]);
    }
    if (t < 64) {  // U = RZ*RY*RX per (l,q)
        const float a  = params[t*3 + 0];
        const float bb = params[t*3 + 1];
        const float c  = params[t*3 + 2];
        const float ha = 0.5f*a, hb = 0.5f*bb, hc = 0.5f*c;
        const float ca = cosf(ha), sa = sinf(ha);
        const float cb = cosf(hb), sb = sinf(hb);
        const float cz = cosf(hc), sz = sinf(hc);
        const c32 m00 = make_float2( cb*ca,  sb*sa);
        const c32 m01 = make_float2(-sb*ca, -cb*sa);
        const c32 m10 = make_float2( sb*ca, -cb*sa);
        const c32 m11 = make_float2( cb*ca, -sb*sa);
        const c32 e0 = make_float2(cz, -sz);
        const c32 e1 = make_float2(cz,  sz);
        Ug[t*4 + 0] = cmul(e0, m00);
        Ug[t*4 + 1] = cmul(e0, m01);
        Ug[t*4 + 2] = cmul(e1, m10);
        Ug[t*4 + 3] = cmul(e1, m11);
    }
    __syncthreads();

    // ---- phase B: w[q,k,i] = U0q[i^k,:]·v_q,  v = (cos h, -i sin h) ---------
    if (t < 64) {
        const int q = t >> 2, k = (t>>1)&1, i = t&1;
        const float h = 0.5f * angles[q];
        const float ch = cosf(h), sh = sinf(h);
        const int r0 = (i ^ k) << 1;
        const c32 u0 = Ug[(q<<2) + r0];
        const c32 u1 = Ug[(q<<2) + r0 + 1];
        wv[t] = make_float2(u0.x*ch + u1.y*sh, u0.y*ch - u1.x*sh);
    }
    __syncthreads();

    // ---- phase C: build compact MPS tensors directly ------------------------
    {
        const int r = t & 7, i = (t>>3)&1, a = t>>4;
        const int m0 = r&1, m1 = (r>>1)&1, m2 = r>>2;
        const int k0 = a&1, k1 = (a>>1)&1, k2 = (a>>2)&1, k3 = a>>3;
        #pragma unroll
        for (int q = 1; q <= 14; ++q) {
            const c32 u3 = Ug[((48+q)<<2) + ((i ^k3)<<1) + m2];
            const c32 u2 = Ug[((32+q)<<2) + ((m2^k2)<<1) + m1];
            const c32 u1 = Ug[((16+q)<<2) + ((m1^k1)<<1) + m0];
            const c32 ww = wv[(q<<2) + (k0<<1) + m0];
            Ac[q-1][a*17 + i*8 + r] = cmul(cmul(u3, u2), cmul(u1, ww));
        }
        if (t < 16) {  // site 0 (k bits absent)
            const c32 u3 = Ug[(48<<2) + (i <<1) + m2];
            const c32 u2 = Ug[(32<<2) + (m2<<1) + m1];
            const c32 u1 = Ug[(16<<2) + (m1<<1) + m0];
            A0c[t] = cmul(cmul(u3, u2), cmul(u1, wv[m0]));
        }
        if (t >= 64 && t < 96) {  // site 15: dense nested 2x2 contractions
            const int idx = t - 64, aa = idx >> 1, ii = idx & 1;
            const int K0 = aa&1, K1 = (aa>>1)&1, K2 = (aa>>2)&1, K3 = aa>>3;
            c32 y1[2], y2[2];
            #pragma unroll
            for (int j1 = 0; j1 < 2; ++j1) {
                const int rr = (j1 ^ K1) << 1;
                y1[j1] = cfma_(Ug[((16+15)<<2)+rr], wv[60 + (K0<<1)],
                         cmul (Ug[((16+15)<<2)+rr+1], wv[60 + (K0<<1) + 1]));
            }
            #pragma unroll
            for (int j2 = 0; j2 < 2; ++j2) {
                const int rr = (j2 ^ K2) << 1;
                y2[j2] = cfma_(Ug[((32+15)<<2)+rr], y1[0],
                         cmul (Ug[((32+15)<<2)+rr+1], y1[1]));
            }
            const int rr = (ii ^ K3) << 1;
            A15v[(aa<<1)+ii] = cfma_(Ug[((48+15)<<2)+rr], y2[0],
                               cmul (Ug[((48+15)<<2)+rr+1], y2[1]));
        }
    }
    __syncthreads();

    // ---- step 0: R_14 init (from A15) and S[0] / L_1 init (from A0c) --------
    if (t < 128) {
        const int m = t>>6, bl = (t>>3)&7, bp = t&7;
        c32 acc = cmulConjA(A15v[((m<<3)+bl)<<1],       A15v[((m<<3)+bp)<<1]);
        acc     = cfmaConjA(A15v[(((m<<3)+bl)<<1) + 1], A15v[(((m<<3)+bp)<<1) + 1], acc);
        Renv[14][m*72 + bl*9 + bp] = acc;
    } else {
        const int u = t-128, i = u>>6, bl = (u>>3)&7, bp = u&7;
        const c32 s = cmulConjA(A0c[(i<<3)+bl], A0c[(i<<3)+bp]);
        Ssto[0][i*72 + bl*9 + bp] = s;
        Lbuf   [i*72 + bl*9 + bp] = s;
    }
    __syncthreads();

    // ---- merged sweep: step s computes R_{14-s} (site 15-s) and S[s]/L_{s+1}
    for (int s = 1; s <= 14; ++s) {
        const c32* Ap = Ac[14 - s];      // site p = 15-s
        const c32* Rn = Renv[15 - s];    // R_p
        const c32* As = Ac[s - 1];       // site s

        // phase 1: two independent K=8 chains per thread
        {
            const int bb = t>>4, i = (t>>3)&1, gp = t&7;
            const int m = bb>>3, al = bb&7;
            c32 tr = make_float2(0.f,0.f), tl = make_float2(0.f,0.f);
            #pragma unroll
            for (int g = 0; g < 8; ++g) {
                tr = cfmaConjA(Ap[bb*17 + i*8 + g], Rn[i*72 + g*9 + gp], tr);
                tl = cfma_(Lbuf[m*72 + al*9 + g], As[(m*8+g)*17 + i*8 + gp], tl);
            }
            TR[bb*17 + i*8 + gp] = tr;
            TL[bb*17 + i*8 + gp] = tl;
        }
        __syncthreads();

        // phase 2: wave-split, K=16 with 2-way accumulator split
        if (t < 128) {
            const int m = t>>6, bl = (t>>3)&7, bp = t&7;
            const c32* trow = &TR[(m*8+bl)*17];
            const c32* arow = &Ap[(m*8+bp)*17];
            c32 r0 = make_float2(0.f,0.f), r1 = make_float2(0.f,0.f);
            #pragma unroll
            for (int ig = 0; ig < 16; ig += 2) {
                r0 = cfma_(trow[ig],   arow[ig],   r0);
                r1 = cfma_(trow[ig+1], arow[ig+1], r1);
            }
            Renv[14-s][m*72 + bl*9 + bp] = cadd(r0, r1);
        } else {
            const int u = t-128, i = u>>6, bl = (u>>3)&7, bp = u&7;
            c32 s0 = make_float2(0.f,0.f), s1 = make_float2(0.f,0.f);
            #pragma unroll
            for (int a = 0; a < 16; a += 2) {
                s0 = cfmaConjA(As[ a   *17 + i*8 + bl], TL[ a   *17 + i*8 + bp], s0);
                s1 = cfmaConjA(As[(a+1)*17 + i*8 + bl], TL[(a+1)*17 + i*8 + bp], s1);
            }
            const c32 sv = cadd(s0, s1);
            Ssto[s][i*72 + bl*9 + bp] = sv;
            Lbuf   [i*72 + bl*9 + bp] = sv;
        }
        __syncthreads();
    }

    // ---- Z phase: Z_q = Re dot(S0-S1, R_q); Z_15 from Lbuf + A15 ------------
    {
        const int q = t >> 4, g = t & 15;
        float val = 0.f;
        if (q < 15) {
            const int i = g>>3, bl = g&7;
            const float sign = i ? -1.f : 1.f;
            const c32* Sq = &Ssto[q][i*72 + bl*9];
            const c32* Rq = &Renv[q][i*72 + bl*9];
            #pragma unroll
            for (int j = 0; j < 8; ++j)
                val += sign * (Sq[j].x*Rq[j].x - Sq[j].y*Rq[j].y);
        } else {
            const int m = g>>3, al = g&7;
            const c32 a0 = A15v[((m*8+al)<<1) + 0];
            const c32 a1 = A15v[((m*8+al)<<1) + 1];
            #pragma unroll
            for (int j = 0; j < 8; ++j) {
                c32 d = cmulConjA(a0, A15v[((m*8+j)<<1) + 0]);
                const c32 d1 = cmulConjA(a1, A15v[((m*8+j)<<1) + 1]);
                d.x -= d1.x; d.y -= d1.y;
                const c32 Lv = Lbuf[m*72 + al*9 + j];
                val += Lv.x*d.x - Lv.y*d.y;
            }
        }
        #pragma unroll
        for (int mm = 8; mm; mm >>= 1) val += __shfl_xor(val, mm);
        if (g == 0) out[b*NQ + q] = val;
    }
}

extern "C" void kernel_launch(void* const* d_in, const int* in_sizes, int n_in,
                              void* d_out, int out_size, void* d_ws, size_t ws_size,
                              hipStream_t stream) {
    const float* ctx    = (const float*)d_in[0];   // [512,256]
    const float* Wm     = (const float*)d_in[1];   // [16,256]
    const float* bias   = (const float*)d_in[2];   // [16]
    const float* params = (const float*)d_in[3];   // [4,16,3]
    float* out = (float*)d_out;                    // [512,16]
    (void)in_sizes; (void)n_in; (void)out_size; (void)d_ws; (void)ws_size;
    pqc_mps_kernel<<<NB, NTH, 0, stream>>>(ctx, Wm, bias, params, out);
}